// Round 6
// baseline (528.357 us; speedup 1.0000x reference)
//
#include <hip/hip_runtime.h>
#include <cstdint>

// ---------------------------------------------------------------------------
// WindowAttention (Swin): B_WIN=4096 windows, N=49 tokens, DIM=256, HEADS=8,
// head_dim=32, NW=64 masks.
// S5 = S4 with k_qkv restructured: BK=64, double-buffered LDS, prefetch
// next K-tile before compute (2-phase pipeline), XOR-swizzled tiles.
// Everything else byte-identical to S4 (passing).
// ---------------------------------------------------------------------------

typedef __attribute__((ext_vector_type(8))) short short8;   // bf16x8 frag
typedef __attribute__((ext_vector_type(4))) float floatx4;  // fp32x4 acc frag

__device__ __forceinline__ ushort f2bf(float f) {
    uint32_t u = __float_as_uint(f);
    u += 0x7FFFu + ((u >> 16) & 1u);   // RNE
    return (ushort)(u >> 16);
}

__device__ __forceinline__ uint32_t cvtpk(float lo, float hi) {
    uint32_t r;
    asm("v_cvt_pk_bf16_f32 %0, %1, %2" : "=v"(r) : "v"(lo), "v"(hi));
    return r;
}

__device__ __forceinline__ void gl_lds16(const void* g, void* lds) {
    __builtin_amdgcn_global_load_lds(
        (const __attribute__((address_space(1))) uint32_t*)g,
        (__attribute__((address_space(3))) uint32_t*)lds, 16, 0, 0);
}

// ---------------------------------------------------------------- kernel 0a
__global__ __launch_bounds__(256) void k_cvt_x(const float* __restrict__ x,
                                               ushort* __restrict__ xb, int n4) {
    int i = blockIdx.x * blockDim.x + threadIdx.x;
    const int stride = gridDim.x * blockDim.x;
    const float4* x4 = (const float4*)x;
    ushort4* o4 = (ushort4*)xb;
    for (; i < n4; i += stride) {
        float4 v = x4[i];
        ushort4 o;
        o.x = f2bf(v.x); o.y = f2bf(v.y); o.z = f2bf(v.z); o.w = f2bf(v.w);
        o4[i] = o;
    }
}

// ---------------------------------------------------------------- kernel 0b
__global__ __launch_bounds__(256) void k_cvt_w(const float* __restrict__ qw,
                                               const float* __restrict__ pw,
                                               ushort* __restrict__ qwb,
                                               ushort* __restrict__ pwb) {
    int i = blockIdx.x * 256 + threadIdx.x;
    if (i < 196608) qwb[i] = f2bf(qw[i]);
    else            pwb[i - 196608] = f2bf(pw[i - 196608]);
}

// ---------------------------------------------------------------- kernel 0c
// comb[wh][n][m] padded to stride 64: comb[wh*4096 + n*64 + m], m-pad zeroed.
__global__ __launch_bounds__(256) void k_comb(const float* __restrict__ mask,
                                              const int* __restrict__ rel,
                                              const float* __restrict__ bt,
                                              float* __restrict__ comb) {
    const int wh = blockIdx.x;
    const int w = wh >> 3, h = wh & 7;
    const float* mw = mask + (size_t)w * 2401;
    float* out = comb + (size_t)wh * 4096;
    for (int e = threadIdx.x; e < 49 * 64; e += 256) {
        const int n = e >> 6, m = e & 63;
        out[e] = (m < 49) ? mw[n * 49 + m] + bt[rel[n * 49 + m] * 8 + h] : 0.0f;
    }
}

// ---------------------------------------------------------------- kernel 1
// qkv gemm_bt: C[tok][c] = sum_k xb[tok][k]*qkv_w[c][k] + qb[c]
// M=200704, N=768, K=256. BM=BN=128, BK=64, 4 K-steps, double-buffered LDS,
// next-tile prefetch issued BEFORE compute (2-phase), one barrier per K-step.
// XOR swizzle (both sides): LDS[R][c'] = glob[R][c' ^ (R&7)], 16B chunks.
// XCD-contiguous block mapping. Epilogue: Q/K row-major [bh][n][dd];
// V transposed [bh][dd][64].
__global__ __launch_bounds__(256) void k_qkv(const ushort* __restrict__ xb,
                                             const ushort* __restrict__ wb,
                                             const float* __restrict__ qb,
                                             ushort* __restrict__ qws,
                                             ushort* __restrict__ kws,
                                             ushort* __restrict__ vws) {
    __shared__ ushort As[2][128 * 64];   // 2 x 16 KB
    __shared__ ushort Bs[2][128 * 64];   // 2 x 16 KB
    const int bid = blockIdx.x;
    const int gid = (bid & 7) * 1176 + (bid >> 3);   // bijective, 9408 = 8*1176
    const int bn = gid % 6, bm = gid / 6;            // 1176 % 6 == 0: no split
    const int t = threadIdx.x;
    const int l = t & 63, w = t >> 6;
    const int wm = w >> 1, wn = w & 1;
    const int li = l & 15, g = l >> 4;

    const ushort* Ag = xb + (size_t)bm * 128 * 256;
    const ushort* Bg = wb + (size_t)bn * 128 * 256;

    // staging: op i covers rows i*32 + w*8 + (l>>3); dest chunk (l&7) of that
    // row holds source chunk (l&7)^(l>>3)  [R&7 == l>>3].
    const int srow_i = w * 8 + (l >> 3);
    const int scol = ((l & 7) ^ (l >> 3)) * 8;       // source col (elems)
    const int dstoff = w * 1024;                      // + i*4096 (+ lane*16 HW)

    const floatx4 zf = {0.f, 0.f, 0.f, 0.f};
    floatx4 acc[4][4];
#pragma unroll
    for (int i = 0; i < 4; ++i)
#pragma unroll
        for (int j = 0; j < 4; ++j) acc[i][j] = zf;

    // prologue: stage K-step 0 into buffer 0
#pragma unroll
    for (int i = 0; i < 4; ++i) {
        gl_lds16(Ag + (size_t)(i * 32 + srow_i) * 256 + scol,
                 (char*)As[0] + i * 4096 + dstoff);
        gl_lds16(Bg + (size_t)(i * 32 + srow_i) * 256 + scol,
                 (char*)Bs[0] + i * 4096 + dstoff);
    }
    __syncthreads();

    int cur = 0;
    for (int kt = 0; kt < 4; ++kt) {
        // issue next K-step's loads first (latency hides under compute)
        if (kt < 3) {
#pragma unroll
            for (int i = 0; i < 4; ++i) {
                gl_lds16(Ag + (size_t)(i * 32 + srow_i) * 256 + (kt + 1) * 64 + scol,
                         (char*)As[cur ^ 1] + i * 4096 + dstoff);
                gl_lds16(Bg + (size_t)(i * 32 + srow_i) * 256 + (kt + 1) * 64 + scol,
                         (char*)Bs[cur ^ 1] + i * 4096 + dstoff);
            }
        }
        const ushort* Ac = As[cur];
        const ushort* Bc = Bs[cur];
#pragma unroll
        for (int ks = 0; ks < 2; ++ks) {
            const int rc = ((ks * 4 + g) ^ (li & 7)) * 8;   // swizzled chunk
            short8 af[4], bfr[4];
#pragma unroll
            for (int mt = 0; mt < 4; ++mt)
                af[mt] = *(const short8*)(Ac + (wm * 64 + mt * 16 + li) * 64 + rc);
#pragma unroll
            for (int nt = 0; nt < 4; ++nt)
                bfr[nt] = *(const short8*)(Bc + (wn * 64 + nt * 16 + li) * 64 + rc);
#pragma unroll
            for (int mt = 0; mt < 4; ++mt)
#pragma unroll
                for (int nt = 0; nt < 4; ++nt)
                    acc[mt][nt] = __builtin_amdgcn_mfma_f32_16x16x32_bf16(
                        af[mt], bfr[nt], acc[mt][nt], 0, 0, 0);
        }
        __syncthreads();
        cur ^= 1;
    }

#pragma unroll
    for (int nt = 0; nt < 4; ++nt) {
        const int c = bn * 128 + wn * 64 + nt * 16 + li;
        const int which = c >> 8, hd = (c >> 5) & 7, dd = c & 31;
        const float bias = qb[c];
        if (which < 2) {
            ushort* dst = which == 0 ? qws : kws;
#pragma unroll
            for (int mt = 0; mt < 4; ++mt)
#pragma unroll
                for (int r = 0; r < 4; ++r) {
                    const int tok = bm * 128 + wm * 64 + mt * 16 + g * 4 + r;
                    const int b = tok / 49;
                    const int n = tok - b * 49;
                    dst[(size_t)(b * 8 + hd) * 1568 + n * 32 + dd] =
                        f2bf(acc[mt][nt][r] + bias);
                }
        } else {
#pragma unroll
            for (int mt = 0; mt < 4; ++mt)
#pragma unroll
                for (int r = 0; r < 4; ++r) {
                    const int tok = bm * 128 + wm * 64 + mt * 16 + g * 4 + r;
                    const int b = tok / 49;
                    const int n = tok - b * 49;
                    vws[(size_t)(b * 8 + hd) * 2048 + dd * 64 + n] =
                        f2bf(acc[mt][nt][r] + bias);
                }
        }
    }
}

// ---------------------------------------------------------------- kernel 2
// Fused attention + projection (S4, unchanged). One block (512 thr) per
// window; wave w = head w. Swapped QK^T, in-lane softmax, pre-normalized P.
// V fragments from transposed vws; pad keys masked in registers (NaN-safe).
__global__ __launch_bounds__(512, 4) void k_attn_proj(
        const ushort* __restrict__ qws, const ushort* __restrict__ kws,
        const ushort* __restrict__ vws, const float* __restrict__ comb,
        const ushort* __restrict__ pwb, const float* __restrict__ pb,
        float* __restrict__ out) {
    __shared__ __align__(16) ushort Pa[8][4608];   // per-wave [64][72]
    const int w = threadIdx.x >> 6, l = threadIdx.x & 63;
    const int b = blockIdx.x, bh = b * 8 + w, wdw = b & 63;
    const int g = l >> 4, li = l & 15;
    ushort* P = Pa[w];
    ushort* ao = (ushort*)Pa;                      // [64][264] aliased

    const ushort* qg = qws + (size_t)bh * 1568;
    const ushort* kg = kws + (size_t)bh * 1568;
    const ushort* vg = vws + (size_t)bh * 2048;

    const short8 z8 = {0, 0, 0, 0, 0, 0, 0, 0};
    short8 qf[4], kf[4];
#pragma unroll
    for (int mt = 0; mt < 4; ++mt) {
        const int n = mt * 16 + li;
        qf[mt] = (n < 49) ? *(const short8*)(qg + n * 32 + g * 8) : z8;
        kf[mt] = (n < 49) ? *(const short8*)(kg + n * 32 + g * 8) : z8;
    }

    short8 vf[2][2];
#pragma unroll
    for (int ks = 0; ks < 2; ++ks)
#pragma unroll
        for (int nt = 0; nt < 2; ++nt)
            vf[ks][nt] = *(const short8*)(vg + (nt * 16 + li) * 64 + ks * 32 + g * 8);
#pragma unroll
    for (int nt = 0; nt < 2; ++nt) {
        if (g == 2) {            // keys 48..55: keep only key 48 (j==0)
            short8 m = z8;
            m[0] = vf[1][nt][0];
            vf[1][nt] = m;
        } else if (g == 3) {     // keys 56..63: all pad
            vf[1][nt] = z8;
        }
    }

    // --- S^T = K Q^T : sac[bq][ak][r] = S[n=bq*16+li][m=ak*16+g*4+r] ---
    const floatx4 zf = {0.f, 0.f, 0.f, 0.f};
    floatx4 sac[4][4];
#pragma unroll
    for (int bq = 0; bq < 4; ++bq)
#pragma unroll
        for (int ak = 0; ak < 4; ++ak)
            sac[bq][ak] = __builtin_amdgcn_mfma_f32_16x16x32_bf16(kf[ak], qf[bq], zf, 0, 0, 0);

    const float* cw = comb + (size_t)(wdw * 8 + w) * 4096;
    const float scale = 0.17677669529663687f;  // 32^-0.5

    // --- in-lane softmax per query tile bq; write normalized bf16 P ---
#pragma unroll
    for (int bq = 0; bq < 4; ++bq) {
        const int n = bq * 16 + li;
        const float* cr = cw + n * 64 + g * 4;
        const float4 c0 = *(const float4*)(cr);
        const float4 c1 = *(const float4*)(cr + 16);
        const float4 c2 = *(const float4*)(cr + 32);
        const float c3x = cr[48];
        float v[12];
        v[0]  = sac[bq][0][0] * scale + c0.x;
        v[1]  = sac[bq][0][1] * scale + c0.y;
        v[2]  = sac[bq][0][2] * scale + c0.z;
        v[3]  = sac[bq][0][3] * scale + c0.w;
        v[4]  = sac[bq][1][0] * scale + c1.x;
        v[5]  = sac[bq][1][1] * scale + c1.y;
        v[6]  = sac[bq][1][2] * scale + c1.z;
        v[7]  = sac[bq][1][3] * scale + c1.w;
        v[8]  = sac[bq][2][0] * scale + c2.x;
        v[9]  = sac[bq][2][1] * scale + c2.y;
        v[10] = sac[bq][2][2] * scale + c2.z;
        v[11] = sac[bq][2][3] * scale + c2.w;
        const float v48 = (g == 0) ? sac[bq][3][0] * scale + c3x : -3.0e38f;
        float mx = fmaxf(fmaxf(fmaxf(v[0], v[1]), fmaxf(v[2], v[3])),
                         fmaxf(fmaxf(v[4], v[5]), fmaxf(v[6], v[7])));
        mx = fmaxf(mx, fmaxf(fmaxf(v[8], v[9]), fmaxf(v[10], v[11])));
        mx = fmaxf(mx, v48);
        mx = fmaxf(mx, __shfl_xor(mx, 16, 64));
        mx = fmaxf(mx, __shfl_xor(mx, 32, 64));
        float e[12], s = 0.f;
#pragma unroll
        for (int i = 0; i < 12; ++i) { e[i] = __expf(v[i] - mx); s += e[i]; }
        const float e48 = __expf(v48 - mx);   // exactly 0 for g>0
        s += e48;
        s += __shfl_xor(s, 16, 64);
        s += __shfl_xor(s, 32, 64);
        const float inv = 1.0f / s;
        uint2 pk;
#pragma unroll
        for (int a = 0; a < 3; ++a) {
            pk.x = cvtpk(e[a * 4 + 0] * inv, e[a * 4 + 1] * inv);
            pk.y = cvtpk(e[a * 4 + 2] * inv, e[a * 4 + 3] * inv);
            *(uint2*)(P + n * 72 + a * 16 + g * 4) = pk;
        }
        pk.x = cvtpk(e48 * inv, 0.f);
        pk.y = 0u;
        *(uint2*)(P + n * 72 + 48 + g * 4) = pk;   // cols 49..63 exact 0
    }

    // --- O = P V ---
    floatx4 oac[4][2];
#pragma unroll
    for (int mt = 0; mt < 4; ++mt)
#pragma unroll
        for (int nt = 0; nt < 2; ++nt) oac[mt][nt] = zf;
#pragma unroll
    for (int ks = 0; ks < 2; ++ks)
#pragma unroll
        for (int mt = 0; mt < 4; ++mt) {
            const short8 pf = *(const short8*)(P + (mt * 16 + li) * 72 + ks * 32 + g * 8);
            oac[mt][0] = __builtin_amdgcn_mfma_f32_16x16x32_bf16(pf, vf[ks][0], oac[mt][0], 0, 0, 0);
            oac[mt][1] = __builtin_amdgcn_mfma_f32_16x16x32_bf16(pf, vf[ks][1], oac[mt][1], 0, 0, 0);
        }

    __syncthreads();   // all waves done with P; safe to alias with ao

    // --- store O (normalized) into ao[n][w*32+dd]; zero rows 49..63 ---
#pragma unroll
    for (int mt = 0; mt < 4; ++mt)
#pragma unroll
        for (int rr = 0; rr < 4; ++rr) {
            const int n = mt * 16 + g * 4 + rr;
            if (n < 49) {
#pragma unroll
                for (int nt = 0; nt < 2; ++nt)
                    ao[n * 264 + w * 32 + nt * 16 + li] = f2bf(oac[mt][nt][rr]);
            }
        }
    for (int idx = l; idx < 240; idx += 64) {
        const int n = 49 + (idx >> 4);
        const int du = idx & 15;
        *(uint32_t*)(ao + n * 264 + w * 32 + du * 2) = 0u;
    }
    __syncthreads();

    // --- proj: out[n][c] = sum_k ao[n][k] * proj_w[c][k] + proj_b[c] ---
    floatx4 pacc[4][2];
#pragma unroll
    for (int mt = 0; mt < 4; ++mt)
#pragma unroll
        for (int nt = 0; nt < 2; ++nt) pacc[mt][nt] = zf;
#pragma unroll
    for (int kt = 0; kt < 8; ++kt) {
        short8 afr[4], wfr[2];
#pragma unroll
        for (int mt = 0; mt < 4; ++mt)
            afr[mt] = *(const short8*)(ao + (mt * 16 + li) * 264 + kt * 32 + g * 8);
#pragma unroll
        for (int nt = 0; nt < 2; ++nt)
            wfr[nt] = *(const short8*)(pwb + (size_t)(w * 32 + nt * 16 + li) * 256 + kt * 32 + g * 8);
#pragma unroll
        for (int mt = 0; mt < 4; ++mt)
#pragma unroll
            for (int nt = 0; nt < 2; ++nt)
                pacc[mt][nt] = __builtin_amdgcn_mfma_f32_16x16x32_bf16(
                    afr[mt], wfr[nt], pacc[mt][nt], 0, 0, 0);
    }

    float* og = out + (size_t)b * 49 * 256;
#pragma unroll
    for (int nt = 0; nt < 2; ++nt) {
        const int c = w * 32 + nt * 16 + li;
        const float bias = pb[c];
#pragma unroll
        for (int mt = 0; mt < 4; ++mt)
#pragma unroll
            for (int r = 0; r < 4; ++r) {
                const int n = mt * 16 + g * 4 + r;
                if (n < 49) og[(size_t)n * 256 + c] = pacc[mt][nt][r] + bias;
            }
    }
}

// ---------------------------------------------------------------------------
extern "C" void kernel_launch(void* const* d_in, const int* in_sizes, int n_in,
                              void* d_out, int out_size, void* d_ws, size_t ws_size,
                              hipStream_t stream) {
    const float* x      = (const float*)d_in[0];
    const float* mask   = (const float*)d_in[1];
    const int*   rel    = (const int*)d_in[2];
    const float* qkv_w  = (const float*)d_in[3];
    const float* qkv_b  = (const float*)d_in[4];
    const float* proj_w = (const float*)d_in[5];
    const float* proj_b = (const float*)d_in[6];
    const float* bt     = (const float*)d_in[7];
    float* out = (float*)d_out;

    // ws layout (bytes); total = 451,411,968 (~431 MiB)
    char* ws = (char*)d_ws;
    ushort* qwb  = (ushort*)(ws);                  // 768*256 bf16   (393216 B)
    ushort* pwb  = (ushort*)(ws + 393216);         // 256*256 bf16   (131072 B)
    float*  comb = (float*) (ws + 524288);         // 512*64*64 f32  (8388608 B)
    ushort* xb   = (ushort*)(ws + 8912896);        // 200704*256 bf16
    ushort* qws  = (ushort*)(ws + 111673344);      // 32768*49*32 bf16
    ushort* kws  = (ushort*)(ws + 214433792);      // 32768*49*32 bf16
    ushort* vws  = (ushort*)(ws + 317194240);      // 32768*32*64 bf16 (transposed)
    (void)ws_size; (void)in_sizes; (void)n_in; (void)out_size;

    k_cvt_x<<<dim3(2048), dim3(256), 0, stream>>>(x, xb, 12845056);
    k_cvt_w<<<dim3(1024), dim3(256), 0, stream>>>(qkv_w, proj_w, qwb, pwb);
    k_comb <<<dim3(512),  dim3(256), 0, stream>>>(mask, rel, bt, comb);
    k_qkv  <<<dim3(9408), dim3(256), 0, stream>>>(xb, qwb, qkv_b, qws, kws, vws);
    k_attn_proj<<<dim3(4096), dim3(512), 0, stream>>>(qws, kws, vws, comb, pwb,
                                                      proj_b, out);
}

// Round 8
// 442.889 us; speedup vs baseline: 1.1930x; 1.1930x over previous
//
#include <hip/hip_runtime.h>
#include <cstdint>

// ---------------------------------------------------------------------------
// WindowAttention (Swin): B_WIN=4096 windows, N=49 tokens, DIM=256, HEADS=8,
// head_dim=32, NW=64 masks.
// S7 = S6 monolithic per-window kernel with the double-scale bug fixed:
// GEMM epilogue stores plain (acc+bias); scale is applied ONCE in softmax
// (S4-verified math verbatim).
// ---------------------------------------------------------------------------

typedef __attribute__((ext_vector_type(8))) short short8;   // bf16x8 frag
typedef __attribute__((ext_vector_type(4))) float floatx4;  // fp32x4 acc frag

__device__ __forceinline__ ushort f2bf(float f) {
    uint32_t u = __float_as_uint(f);
    u += 0x7FFFu + ((u >> 16) & 1u);   // RNE
    return (ushort)(u >> 16);
}

__device__ __forceinline__ uint32_t cvtpk(float lo, float hi) {
    uint32_t r;
    asm("v_cvt_pk_bf16_f32 %0, %1, %2" : "=v"(r) : "v"(lo), "v"(hi));
    return r;
}

// ---------------------------------------------------------------- kernel 0b
__global__ __launch_bounds__(256) void k_cvt_w(const float* __restrict__ qw,
                                               const float* __restrict__ pw,
                                               ushort* __restrict__ qwb,
                                               ushort* __restrict__ pwb) {
    int i = blockIdx.x * 256 + threadIdx.x;
    if (i < 196608) qwb[i] = f2bf(qw[i]);
    else            pwb[i - 196608] = f2bf(pw[i - 196608]);
}

// ---------------------------------------------------------------- kernel 0c
// comb[wh][n][m] padded to stride 64: comb[wh*4096 + n*64 + m], m-pad zeroed.
__global__ __launch_bounds__(256) void k_comb(const float* __restrict__ mask,
                                              const int* __restrict__ rel,
                                              const float* __restrict__ bt,
                                              float* __restrict__ comb) {
    const int wh = blockIdx.x;
    const int w = wh >> 3, h = wh & 7;
    const float* mw = mask + (size_t)w * 2401;
    float* out = comb + (size_t)wh * 4096;
    for (int e = threadIdx.x; e < 49 * 64; e += 256) {
        const int n = e >> 6, m = e & 63;
        out[e] = (m < 49) ? mw[n * 49 + m] + bt[rel[n * 49 + m] * 8 + h] : 0.0f;
    }
}

// ---------------------------------------------------------------- kernel 1
// Monolithic per-window kernel. Block = 512 thr (8 waves), one window blk.
// LDS (ushort units):
//   xb    [0,16384)      : x window bf16 [64][256], 16B-chunk j^(n&7) swizzle
//   q_lds [16384,33280)  : q [64][264]  (stride 264)
//   k_lds [33280,50176)  : k [64][264]
//   vt    [50176,68608)  : v transposed [256][72] (row = head*32+dd, col = n)
//   P[w]  = smem + w*4608: [64][72] — aliases xb/q/k AFTER frag-load barrier
//   ao    = smem [0,16896): [64][264] — aliases P[0..3] AFTER PV barrier
// Phases: stage-x | GEMM+epilogue | frag-load | softmax+PV | ao-store | proj.
__global__ __launch_bounds__(512, 2) void k_mono(
        const ushort* __restrict__ qwb, const float* __restrict__ x,
        const float* __restrict__ qb, const float* __restrict__ comb,
        const ushort* __restrict__ pwb, const float* __restrict__ pb,
        float* __restrict__ out) {
    __shared__ ushort smem[68608];   // 137,216 B
    ushort* xb    = smem;
    ushort* q_lds = smem + 16384;
    ushort* k_lds = smem + 33280;
    ushort* vt    = smem + 50176;

    const int t = threadIdx.x;
    const int w = t >> 6, l = t & 63;
    const int g = l >> 4, li = l & 15;
    const int blk = blockIdx.x;
    const int wdw = blk & 63;

    // ---- phase 0: stage x -> xb (bf16, chunk-swizzled), zero pad rows ----
    {
        const int n = t >> 3, seg = t & 7;
        if (n < 49) {
            const float* src = x + ((size_t)blk * 49 + n) * 256 + seg * 32;
#pragma unroll
            for (int c4 = 0; c4 < 4; ++c4) {
                const float4 a  = *(const float4*)(src + c4 * 8);
                const float4 b2 = *(const float4*)(src + c4 * 8 + 4);
                uint4 u;
                u.x = cvtpk(a.x, a.y);  u.y = cvtpk(a.z, a.w);
                u.z = cvtpk(b2.x, b2.y); u.w = cvtpk(b2.z, b2.w);
                const int j = seg * 4 + c4;
                *(uint4*)(xb + n * 256 + ((j ^ (n & 7)) * 8)) = u;
            }
        } else {
            const uint4 z = {0u, 0u, 0u, 0u};
#pragma unroll
            for (int c4 = 0; c4 < 4; ++c4) {
                const int j = seg * 4 + c4;
                *(uint4*)(xb + n * 256 + ((j ^ (n & 7)) * 8)) = z;
            }
        }
    }
    __syncthreads();

    const floatx4 zf = {0.f, 0.f, 0.f, 0.f};
    const float scale = 0.17677669529663687f;  // 32^-0.5

    // ---- phase 1: qkv GEMM. acc[ct][nt] = D[c][n], wave w owns c-tiles
    //      w*6..w*6+5 (c in [w*96, w*96+96)). A = W rows (global L2),
    //      B = x rows (xb LDS). D lane map: c = base+g*4+r, n = tile+li. ----
    {
        floatx4 acc[6][4];
#pragma unroll
        for (int i = 0; i < 6; ++i)
#pragma unroll
            for (int j = 0; j < 4; ++j) acc[i][j] = zf;

#pragma unroll
        for (int kt = 0; kt < 8; ++kt) {
            short8 af[6], bfr[4];
#pragma unroll
            for (int ct = 0; ct < 6; ++ct)
                af[ct] = *(const short8*)(qwb +
                    (size_t)(w * 96 + ct * 16 + li) * 256 + kt * 32 + g * 8);
#pragma unroll
            for (int nt = 0; nt < 4; ++nt)
                bfr[nt] = *(const short8*)(xb + (nt * 16 + li) * 256 +
                    (((kt * 4 + g) ^ (li & 7)) * 8));
#pragma unroll
            for (int ct = 0; ct < 6; ++ct)
#pragma unroll
                for (int nt = 0; nt < 4; ++nt)
                    acc[ct][nt] = __builtin_amdgcn_mfma_f32_16x16x32_bf16(
                        af[ct], bfr[nt], acc[ct][nt], 0, 0, 0);
        }

        // epilogue: scatter into q_lds / k_lds / vt (plain acc+bias; scale
        // is applied ONCE later, in the softmax)
#pragma unroll
        for (int ct = 0; ct < 6; ++ct) {
            const int cb = w * 96 + ct * 16 + g * 4;   // c of r=0 (mult of 4)
            const int which = cb >> 8, head = (cb >> 5) & 7, dd0 = cb & 31;
            const float4 b4 = *(const float4*)(qb + cb);
#pragma unroll
            for (int nt = 0; nt < 4; ++nt) {
                const int n = nt * 16 + li;
                const float v0 = acc[ct][nt][0] + b4.x;
                const float v1 = acc[ct][nt][1] + b4.y;
                const float v2 = acc[ct][nt][2] + b4.z;
                const float v3 = acc[ct][nt][3] + b4.w;
                if (which < 2) {
                    ushort* dst = (which == 0) ? q_lds : k_lds;
                    uint2 pk2;
                    pk2.x = cvtpk(v0, v1);
                    pk2.y = cvtpk(v2, v3);
                    *(uint2*)(dst + n * 264 + head * 32 + dd0) = pk2;
                } else {
                    const int rb = head * 32 + dd0;
                    vt[(rb + 0) * 72 + n] = f2bf(v0);
                    vt[(rb + 1) * 72 + n] = f2bf(v1);
                    vt[(rb + 2) * 72 + n] = f2bf(v2);
                    vt[(rb + 3) * 72 + n] = f2bf(v3);
                }
            }
        }
    }
    __syncthreads();

    // ---- phase 2: attention, wave w = head w (S4 math verbatim) ----
    ushort* P  = smem + w * 4608;      // [64][72], aliases xb/q/k (see below)
    ushort* ao = smem;                 // [64][264], aliases P[0..3] later

    short8 qf[4], kf[4], vf[2][2];
#pragma unroll
    for (int mt = 0; mt < 4; ++mt) {
        qf[mt] = *(const short8*)(q_lds + (mt * 16 + li) * 264 + w * 32 + g * 8);
        kf[mt] = *(const short8*)(k_lds + (mt * 16 + li) * 264 + w * 32 + g * 8);
    }
#pragma unroll
    for (int ks = 0; ks < 2; ++ks)
#pragma unroll
        for (int nt = 0; nt < 2; ++nt)
            vf[ks][nt] = *(const short8*)(vt + (w * 32 + nt * 16 + li) * 72 +
                                          ks * 32 + g * 8);
    __syncthreads();   // all frags in regs: xb/q/k now dead -> P may overwrite

    // S^T = K Q^T : sac[bq][ak][r] = S[n=bq*16+li][m=ak*16+g*4+r]
    floatx4 sac[4][4];
#pragma unroll
    for (int bq = 0; bq < 4; ++bq)
#pragma unroll
        for (int ak = 0; ak < 4; ++ak)
            sac[bq][ak] = __builtin_amdgcn_mfma_f32_16x16x32_bf16(
                kf[ak], qf[bq], zf, 0, 0, 0);

    const float* cw = comb + (size_t)(wdw * 8 + w) * 4096;

    // in-lane softmax per query tile bq; write normalized bf16 P
#pragma unroll
    for (int bq = 0; bq < 4; ++bq) {
        const int n = bq * 16 + li;
        const float* cr = cw + n * 64 + g * 4;
        const float4 c0 = *(const float4*)(cr);
        const float4 c1 = *(const float4*)(cr + 16);
        const float4 c2 = *(const float4*)(cr + 32);
        const float c3x = cr[48];
        float v[12];
        v[0]  = sac[bq][0][0] * scale + c0.x;
        v[1]  = sac[bq][0][1] * scale + c0.y;
        v[2]  = sac[bq][0][2] * scale + c0.z;
        v[3]  = sac[bq][0][3] * scale + c0.w;
        v[4]  = sac[bq][1][0] * scale + c1.x;
        v[5]  = sac[bq][1][1] * scale + c1.y;
        v[6]  = sac[bq][1][2] * scale + c1.z;
        v[7]  = sac[bq][1][3] * scale + c1.w;
        v[8]  = sac[bq][2][0] * scale + c2.x;
        v[9]  = sac[bq][2][1] * scale + c2.y;
        v[10] = sac[bq][2][2] * scale + c2.z;
        v[11] = sac[bq][2][3] * scale + c2.w;
        const float v48 = (g == 0) ? sac[bq][3][0] * scale + c3x : -3.0e38f;
        float mx = fmaxf(fmaxf(fmaxf(v[0], v[1]), fmaxf(v[2], v[3])),
                         fmaxf(fmaxf(v[4], v[5]), fmaxf(v[6], v[7])));
        mx = fmaxf(mx, fmaxf(fmaxf(v[8], v[9]), fmaxf(v[10], v[11])));
        mx = fmaxf(mx, v48);
        mx = fmaxf(mx, __shfl_xor(mx, 16, 64));
        mx = fmaxf(mx, __shfl_xor(mx, 32, 64));
        float e[12], s = 0.f;
#pragma unroll
        for (int i = 0; i < 12; ++i) { e[i] = __expf(v[i] - mx); s += e[i]; }
        const float e48 = __expf(v48 - mx);   // exactly 0 for g>0
        s += e48;
        s += __shfl_xor(s, 16, 64);
        s += __shfl_xor(s, 32, 64);
        const float inv = 1.0f / s;
        uint2 pk;
#pragma unroll
        for (int a = 0; a < 3; ++a) {
            pk.x = cvtpk(e[a * 4 + 0] * inv, e[a * 4 + 1] * inv);
            pk.y = cvtpk(e[a * 4 + 2] * inv, e[a * 4 + 3] * inv);
            *(uint2*)(P + n * 72 + a * 16 + g * 4) = pk;
        }
        pk.x = cvtpk(e48 * inv, 0.f);
        pk.y = 0u;
        *(uint2*)(P + n * 72 + 48 + g * 4) = pk;   // cols 49..63 exact 0
    }

    // O = P V (P wave-private; vt read-only; P pad cols exact 0 x finite
    // vt pad -> contributes 0, NaN-safe)
    floatx4 oac[4][2];
#pragma unroll
    for (int mt = 0; mt < 4; ++mt)
#pragma unroll
        for (int nt = 0; nt < 2; ++nt) oac[mt][nt] = zf;
#pragma unroll
    for (int ks = 0; ks < 2; ++ks)
#pragma unroll
        for (int mt = 0; mt < 4; ++mt) {
            const short8 pf = *(const short8*)(P + (mt * 16 + li) * 72 +
                                               ks * 32 + g * 8);
            oac[mt][0] = __builtin_amdgcn_mfma_f32_16x16x32_bf16(
                pf, vf[ks][0], oac[mt][0], 0, 0, 0);
            oac[mt][1] = __builtin_amdgcn_mfma_f32_16x16x32_bf16(
                pf, vf[ks][1], oac[mt][1], 0, 0, 0);
        }

    __syncthreads();   // all waves done with P: ao may overwrite

    // store O (normalized) into ao[n][w*32+dd]; zero rows 49..63
#pragma unroll
    for (int mt = 0; mt < 4; ++mt)
#pragma unroll
        for (int rr = 0; rr < 4; ++rr) {
            const int n = mt * 16 + g * 4 + rr;
            if (n < 49) {
#pragma unroll
                for (int nt = 0; nt < 2; ++nt)
                    ao[n * 264 + w * 32 + nt * 16 + li] = f2bf(oac[mt][nt][rr]);
            }
        }
    for (int idx = l; idx < 240; idx += 64) {
        const int n = 49 + (idx >> 4);
        const int du = idx & 15;
        *(uint32_t*)(ao + n * 264 + w * 32 + du * 2) = 0u;
    }
    __syncthreads();

    // proj: out[n][c] = sum_k ao[n][k] * proj_w[c][k] + proj_b[c]
    floatx4 pacc[4][2];
#pragma unroll
    for (int mt = 0; mt < 4; ++mt)
#pragma unroll
        for (int nt = 0; nt < 2; ++nt) pacc[mt][nt] = zf;
#pragma unroll
    for (int kt = 0; kt < 8; ++kt) {
        short8 afr[4], wfr[2];
#pragma unroll
        for (int mt = 0; mt < 4; ++mt)
            afr[mt] = *(const short8*)(ao + (mt * 16 + li) * 264 + kt * 32 + g * 8);
#pragma unroll
        for (int nt = 0; nt < 2; ++nt)
            wfr[nt] = *(const short8*)(pwb +
                (size_t)(w * 32 + nt * 16 + li) * 256 + kt * 32 + g * 8);
#pragma unroll
        for (int mt = 0; mt < 4; ++mt)
#pragma unroll
            for (int nt = 0; nt < 2; ++nt)
                pacc[mt][nt] = __builtin_amdgcn_mfma_f32_16x16x32_bf16(
                    afr[mt], wfr[nt], pacc[mt][nt], 0, 0, 0);
    }

    float* og = out + (size_t)blk * 49 * 256;
#pragma unroll
    for (int nt = 0; nt < 2; ++nt) {
        const int c = w * 32 + nt * 16 + li;
        const float bias = pb[c];
#pragma unroll
        for (int mt = 0; mt < 4; ++mt)
#pragma unroll
            for (int r = 0; r < 4; ++r) {
                const int n = mt * 16 + g * 4 + r;
                if (n < 49) og[(size_t)n * 256 + c] = pacc[mt][nt][r] + bias;
            }
    }
}

// ---------------------------------------------------------------------------
extern "C" void kernel_launch(void* const* d_in, const int* in_sizes, int n_in,
                              void* d_out, int out_size, void* d_ws, size_t ws_size,
                              hipStream_t stream) {
    const float* x      = (const float*)d_in[0];
    const float* mask   = (const float*)d_in[1];
    const int*   rel    = (const int*)d_in[2];
    const float* qkv_w  = (const float*)d_in[3];
    const float* qkv_b  = (const float*)d_in[4];
    const float* proj_w = (const float*)d_in[5];
    const float* proj_b = (const float*)d_in[6];
    const float* bt     = (const float*)d_in[7];
    float* out = (float*)d_out;

    // ws layout (bytes); total = 8,912,896 (~8.5 MiB)
    char* ws = (char*)d_ws;
    ushort* qwb  = (ushort*)(ws);                  // 768*256 bf16   (393216 B)
    ushort* pwb  = (ushort*)(ws + 393216);         // 256*256 bf16   (131072 B)
    float*  comb = (float*) (ws + 524288);         // 512*64*64 f32  (8388608 B)
    (void)ws_size; (void)in_sizes; (void)n_in; (void)out_size;

    k_cvt_w<<<dim3(1024), dim3(256), 0, stream>>>(qkv_w, proj_w, qwb, pwb);
    k_comb <<<dim3(512),  dim3(256), 0, stream>>>(mask, rel, bt, comb);
    k_mono <<<dim3(4096), dim3(512), 0, stream>>>(qwb, x, qkv_b, comb, pwb,
                                                  proj_b, out);
}

// Round 9
// 411.510 us; speedup vs baseline: 1.2839x; 1.0763x over previous
//
#include <hip/hip_runtime.h>
#include <cstdint>

// ---------------------------------------------------------------------------
// WindowAttention (Swin): B_WIN=4096 windows, N=49 tokens, DIM=256, HEADS=8,
// head_dim=32, NW=64 masks.
// S8 = S7 monolithic kernel re-tiled per-head so Q/K/V exchange is wave-
// private: LDS 137KB -> 77.8KB -> 2 blocks/CU. Math identical to S7.
// ---------------------------------------------------------------------------

typedef __attribute__((ext_vector_type(8))) short short8;   // bf16x8 frag
typedef __attribute__((ext_vector_type(4))) float floatx4;  // fp32x4 acc frag

__device__ __forceinline__ ushort f2bf(float f) {
    uint32_t u = __float_as_uint(f);
    u += 0x7FFFu + ((u >> 16) & 1u);   // RNE
    return (ushort)(u >> 16);
}

__device__ __forceinline__ uint32_t cvtpk(float lo, float hi) {
    uint32_t r;
    asm("v_cvt_pk_bf16_f32 %0, %1, %2" : "=v"(r) : "v"(lo), "v"(hi));
    return r;
}

// ---------------------------------------------------------------- kernel 0b
__global__ __launch_bounds__(256) void k_cvt_w(const float* __restrict__ qw,
                                               const float* __restrict__ pw,
                                               ushort* __restrict__ qwb,
                                               ushort* __restrict__ pwb) {
    int i = blockIdx.x * 256 + threadIdx.x;
    if (i < 196608) qwb[i] = f2bf(qw[i]);
    else            pwb[i - 196608] = f2bf(pw[i - 196608]);
}

// ---------------------------------------------------------------- kernel 0c
// comb[wh][n][m] padded to stride 64: comb[wh*4096 + n*64 + m], m-pad zeroed.
__global__ __launch_bounds__(256) void k_comb(const float* __restrict__ mask,
                                              const int* __restrict__ rel,
                                              const float* __restrict__ bt,
                                              float* __restrict__ comb) {
    const int wh = blockIdx.x;
    const int w = wh >> 3, h = wh & 7;
    const float* mw = mask + (size_t)w * 2401;
    float* out = comb + (size_t)wh * 4096;
    for (int e = threadIdx.x; e < 49 * 64; e += 256) {
        const int n = e >> 6, m = e & 63;
        out[e] = (m < 49) ? mw[n * 49 + m] + bt[rel[n * 49 + m] * 8 + h] : 0.0f;
    }
}

// ---------------------------------------------------------------- kernel 1
// Monolithic per-window kernel, per-head wave tiling. 512 thr (8 waves).
// LDS (ushort units), total 38912 ush = 77824 B -> 2 blocks/CU:
//   per-wave region R[w] = smem + w*4864, size 4864 ush (9728 B):
//     scrQK = R[w][0,2560)    : [64][40] q then k scratch (wave-private)
//     vtw   = R[w][2560,4864) : [32][72] v transposed (wave-private)
//     P     = R[w][0,4608)    : [64][72] softmax out (after frags in regs)
//   xb = smem[0,16384) : x bf16 [64][256] swizzled — dead after GEMM K-loop,
//        aliases R[0..3] (barrier-protected)
//   ao = smem[0,16896) : [64][264] — aliases R[0..3] P (after PV barrier)
// Phases: stage-x | GEMM K-loop | epilogue+attention (wave-private) |
//         ao-store | proj.  4 barriers.
__global__ __launch_bounds__(512, 2) void k_mono(
        const ushort* __restrict__ qwb, const float* __restrict__ x,
        const float* __restrict__ qb, const float* __restrict__ comb,
        const ushort* __restrict__ pwb, const float* __restrict__ pb,
        float* __restrict__ out) {
    __shared__ ushort smem[38912];   // 77,824 B
    ushort* xb = smem;

    const int t = threadIdx.x;
    const int w = t >> 6, l = t & 63;
    const int g = l >> 4, li = l & 15;
    const int blk = blockIdx.x;
    const int wdw = blk & 63;

    ushort* scr = smem + w * 4864;          // [64][40]
    ushort* vtw = smem + w * 4864 + 2560;   // [32][72]
    ushort* P   = smem + w * 4864;          // [64][72]
    ushort* ao  = smem;                     // [64][264]

    // ---- phase 0: stage x -> xb (bf16, 16B-chunk j^(n&7) swizzle) ----
    {
        const int n = t >> 3, seg = t & 7;
        if (n < 49) {
            const float* src = x + ((size_t)blk * 49 + n) * 256 + seg * 32;
#pragma unroll
            for (int c4 = 0; c4 < 4; ++c4) {
                const float4 a  = *(const float4*)(src + c4 * 8);
                const float4 b2 = *(const float4*)(src + c4 * 8 + 4);
                uint4 u;
                u.x = cvtpk(a.x, a.y);  u.y = cvtpk(a.z, a.w);
                u.z = cvtpk(b2.x, b2.y); u.w = cvtpk(b2.z, b2.w);
                const int j = seg * 4 + c4;
                *(uint4*)(xb + n * 256 + ((j ^ (n & 7)) * 8)) = u;
            }
        } else {
            const uint4 z = {0u, 0u, 0u, 0u};
#pragma unroll
            for (int c4 = 0; c4 < 4; ++c4) {
                const int j = seg * 4 + c4;
                *(uint4*)(xb + n * 256 + ((j ^ (n & 7)) * 8)) = z;
            }
        }
    }
    __syncthreads();

    const floatx4 zf = {0.f, 0.f, 0.f, 0.f};
    const float scale = 0.17677669529663687f;  // 32^-0.5

    // ---- phase 1: qkv GEMM, per-head tiles. Wave w owns head w's columns:
    //      tiles {q: w*32+0/16, k: 256+w*32+0/16, v: 512+w*32+0/16}. ----
    const int rowbase[6] = {w * 32,       w * 32 + 16,
                            256 + w * 32, 256 + w * 32 + 16,
                            512 + w * 32, 512 + w * 32 + 16};
    floatx4 acc[6][4];
#pragma unroll
    for (int i = 0; i < 6; ++i)
#pragma unroll
        for (int j = 0; j < 4; ++j) acc[i][j] = zf;

#pragma unroll
    for (int kt = 0; kt < 8; ++kt) {
        short8 af[6], bfr[4];
#pragma unroll
        for (int ct = 0; ct < 6; ++ct)
            af[ct] = *(const short8*)(qwb +
                (size_t)(rowbase[ct] + li) * 256 + kt * 32 + g * 8);
#pragma unroll
        for (int nt = 0; nt < 4; ++nt)
            bfr[nt] = *(const short8*)(xb + (nt * 16 + li) * 256 +
                (((kt * 4 + g) ^ (li & 7)) * 8));
#pragma unroll
        for (int ct = 0; ct < 6; ++ct)
#pragma unroll
            for (int nt = 0; nt < 4; ++nt)
                acc[ct][nt] = __builtin_amdgcn_mfma_f32_16x16x32_bf16(
                    af[ct], bfr[nt], acc[ct][nt], 0, 0, 0);
    }
    __syncthreads();   // xb dead: wave-private scratch (aliasing xb) may write

    // ---- phase 2 (wave-private, no block barriers): epilogue + attention ---
    short8 qf[4], kf[4], vf[2][2];

    // Q: acc tiles 0,1 -> scr, then frags
#pragma unroll
    for (int ct = 0; ct < 2; ++ct) {
        const int dd0 = ct * 16 + g * 4;
        const float4 b4 = *(const float4*)(qb + w * 32 + dd0);
#pragma unroll
        for (int nt = 0; nt < 4; ++nt) {
            const int n = nt * 16 + li;
            uint2 pk2;
            pk2.x = cvtpk(acc[ct][nt][0] + b4.x, acc[ct][nt][1] + b4.y);
            pk2.y = cvtpk(acc[ct][nt][2] + b4.z, acc[ct][nt][3] + b4.w);
            *(uint2*)(scr + n * 40 + dd0) = pk2;
        }
    }
#pragma unroll
    for (int mt = 0; mt < 4; ++mt)
        qf[mt] = *(const short8*)(scr + (mt * 16 + li) * 40 + g * 8);

    // K: acc tiles 2,3 -> scr (overwrite; wave-private in-order), then frags
#pragma unroll
    for (int ct = 2; ct < 4; ++ct) {
        const int dd0 = (ct - 2) * 16 + g * 4;
        const float4 b4 = *(const float4*)(qb + 256 + w * 32 + dd0);
#pragma unroll
        for (int nt = 0; nt < 4; ++nt) {
            const int n = nt * 16 + li;
            uint2 pk2;
            pk2.x = cvtpk(acc[ct][nt][0] + b4.x, acc[ct][nt][1] + b4.y);
            pk2.y = cvtpk(acc[ct][nt][2] + b4.z, acc[ct][nt][3] + b4.w);
            *(uint2*)(scr + n * 40 + dd0) = pk2;
        }
    }
#pragma unroll
    for (int mt = 0; mt < 4; ++mt)
        kf[mt] = *(const short8*)(scr + (mt * 16 + li) * 40 + g * 8);

    // V: acc tiles 4,5 -> vtw transposed [dd][n], then frags
#pragma unroll
    for (int ct = 4; ct < 6; ++ct) {
        const int dd0 = (ct - 4) * 16 + g * 4;
        const float4 b4 = *(const float4*)(qb + 512 + w * 32 + dd0);
#pragma unroll
        for (int nt = 0; nt < 4; ++nt) {
            const int n = nt * 16 + li;
            vtw[(dd0 + 0) * 72 + n] = f2bf(acc[ct][nt][0] + b4.x);
            vtw[(dd0 + 1) * 72 + n] = f2bf(acc[ct][nt][1] + b4.y);
            vtw[(dd0 + 2) * 72 + n] = f2bf(acc[ct][nt][2] + b4.z);
            vtw[(dd0 + 3) * 72 + n] = f2bf(acc[ct][nt][3] + b4.w);
        }
    }
#pragma unroll
    for (int ks = 0; ks < 2; ++ks)
#pragma unroll
        for (int nt = 0; nt < 2; ++nt)
            vf[ks][nt] = *(const short8*)(vtw + (nt * 16 + li) * 72 +
                                          ks * 32 + g * 8);

    // S^T = K Q^T : sac[bq][ak][r] = S[n=bq*16+li][m=ak*16+g*4+r]
    floatx4 sac[4][4];
#pragma unroll
    for (int bq = 0; bq < 4; ++bq)
#pragma unroll
        for (int ak = 0; ak < 4; ++ak)
            sac[bq][ak] = __builtin_amdgcn_mfma_f32_16x16x32_bf16(
                kf[ak], qf[bq], zf, 0, 0, 0);

    const float* cw = comb + (size_t)(wdw * 8 + w) * 4096;

    // in-lane softmax per query tile bq; write normalized bf16 P
    // (P overwrites scr+vtw: qf/kf/vf all in regs, wave-private in-order)
#pragma unroll
    for (int bq = 0; bq < 4; ++bq) {
        const int n = bq * 16 + li;
        const float* cr = cw + n * 64 + g * 4;
        const float4 c0 = *(const float4*)(cr);
        const float4 c1 = *(const float4*)(cr + 16);
        const float4 c2 = *(const float4*)(cr + 32);
        const float c3x = cr[48];
        float v[12];
        v[0]  = sac[bq][0][0] * scale + c0.x;
        v[1]  = sac[bq][0][1] * scale + c0.y;
        v[2]  = sac[bq][0][2] * scale + c0.z;
        v[3]  = sac[bq][0][3] * scale + c0.w;
        v[4]  = sac[bq][1][0] * scale + c1.x;
        v[5]  = sac[bq][1][1] * scale + c1.y;
        v[6]  = sac[bq][1][2] * scale + c1.z;
        v[7]  = sac[bq][1][3] * scale + c1.w;
        v[8]  = sac[bq][2][0] * scale + c2.x;
        v[9]  = sac[bq][2][1] * scale + c2.y;
        v[10] = sac[bq][2][2] * scale + c2.z;
        v[11] = sac[bq][2][3] * scale + c2.w;
        const float v48 = (g == 0) ? sac[bq][3][0] * scale + c3x : -3.0e38f;
        float mx = fmaxf(fmaxf(fmaxf(v[0], v[1]), fmaxf(v[2], v[3])),
                         fmaxf(fmaxf(v[4], v[5]), fmaxf(v[6], v[7])));
        mx = fmaxf(mx, fmaxf(fmaxf(v[8], v[9]), fmaxf(v[10], v[11])));
        mx = fmaxf(mx, v48);
        mx = fmaxf(mx, __shfl_xor(mx, 16, 64));
        mx = fmaxf(mx, __shfl_xor(mx, 32, 64));
        float e[12], s = 0.f;
#pragma unroll
        for (int i = 0; i < 12; ++i) { e[i] = __expf(v[i] - mx); s += e[i]; }
        const float e48 = __expf(v48 - mx);   // exactly 0 for g>0
        s += e48;
        s += __shfl_xor(s, 16, 64);
        s += __shfl_xor(s, 32, 64);
        const float inv = 1.0f / s;
        uint2 pk;
#pragma unroll
        for (int a = 0; a < 3; ++a) {
            pk.x = cvtpk(e[a * 4 + 0] * inv, e[a * 4 + 1] * inv);
            pk.y = cvtpk(e[a * 4 + 2] * inv, e[a * 4 + 3] * inv);
            *(uint2*)(P + n * 72 + a * 16 + g * 4) = pk;
        }
        pk.x = cvtpk(e48 * inv, 0.f);
        pk.y = 0u;
        *(uint2*)(P + n * 72 + 48 + g * 4) = pk;   // cols 49..63 exact 0
    }

    // O = P V (wave-private)
    floatx4 oac[4][2];
#pragma unroll
    for (int mt = 0; mt < 4; ++mt)
#pragma unroll
        for (int nt = 0; nt < 2; ++nt) oac[mt][nt] = zf;
#pragma unroll
    for (int ks = 0; ks < 2; ++ks)
#pragma unroll
        for (int mt = 0; mt < 4; ++mt) {
            const short8 pf = *(const short8*)(P + (mt * 16 + li) * 72 +
                                               ks * 32 + g * 8);
            oac[mt][0] = __builtin_amdgcn_mfma_f32_16x16x32_bf16(
                pf, vf[ks][0], oac[mt][0], 0, 0, 0);
            oac[mt][1] = __builtin_amdgcn_mfma_f32_16x16x32_bf16(
                pf, vf[ks][1], oac[mt][1], 0, 0, 0);
        }

    __syncthreads();   // all waves done with P: ao may overwrite

    // ---- phase 3: store O (normalized) into ao[n][w*32+dd]; zero pads ----
#pragma unroll
    for (int mt = 0; mt < 4; ++mt)
#pragma unroll
        for (int rr = 0; rr < 4; ++rr) {
            const int n = mt * 16 + g * 4 + rr;
            if (n < 49) {
#pragma unroll
                for (int nt = 0; nt < 2; ++nt)
                    ao[n * 264 + w * 32 + nt * 16 + li] = f2bf(oac[mt][nt][rr]);
            }
        }
    for (int idx = l; idx < 240; idx += 64) {
        const int n = 49 + (idx >> 4);
        const int du = idx & 15;
        *(uint32_t*)(ao + n * 264 + w * 32 + du * 2) = 0u;
    }
    __syncthreads();

    // ---- phase 4: proj: out[n][c] = sum_k ao[n][k]*proj_w[c][k] + pb[c] ----
    floatx4 pacc[4][2];
#pragma unroll
    for (int mt = 0; mt < 4; ++mt)
#pragma unroll
        for (int nt = 0; nt < 2; ++nt) pacc[mt][nt] = zf;
#pragma unroll
    for (int kt = 0; kt < 8; ++kt) {
        short8 afr[4], wfr[2];
#pragma unroll
        for (int mt = 0; mt < 4; ++mt)
            afr[mt] = *(const short8*)(ao + (mt * 16 + li) * 264 + kt * 32 + g * 8);
#pragma unroll
        for (int nt = 0; nt < 2; ++nt)
            wfr[nt] = *(const short8*)(pwb +
                (size_t)(w * 32 + nt * 16 + li) * 256 + kt * 32 + g * 8);
#pragma unroll
        for (int mt = 0; mt < 4; ++mt)
#pragma unroll
            for (int nt = 0; nt < 2; ++nt)
                pacc[mt][nt] = __builtin_amdgcn_mfma_f32_16x16x32_bf16(
                    afr[mt], wfr[nt], pacc[mt][nt], 0, 0, 0);
    }

    float* og = out + (size_t)blk * 49 * 256;
#pragma unroll
    for (int nt = 0; nt < 2; ++nt) {
        const int c = w * 32 + nt * 16 + li;
        const float bias = pb[c];
#pragma unroll
        for (int mt = 0; mt < 4; ++mt)
#pragma unroll
            for (int r = 0; r < 4; ++r) {
                const int n = mt * 16 + g * 4 + r;
                if (n < 49) og[(size_t)n * 256 + c] = pacc[mt][nt][r] + bias;
            }
    }
}

// ---------------------------------------------------------------------------
extern "C" void kernel_launch(void* const* d_in, const int* in_sizes, int n_in,
                              void* d_out, int out_size, void* d_ws, size_t ws_size,
                              hipStream_t stream) {
    const float* x      = (const float*)d_in[0];
    const float* mask   = (const float*)d_in[1];
    const int*   rel    = (const int*)d_in[2];
    const float* qkv_w  = (const float*)d_in[3];
    const float* qkv_b  = (const float*)d_in[4];
    const float* proj_w = (const float*)d_in[5];
    const float* proj_b = (const float*)d_in[6];
    const float* bt     = (const float*)d_in[7];
    float* out = (float*)d_out;

    // ws layout (bytes); total = 8,912,896 (~8.5 MiB)
    char* ws = (char*)d_ws;
    ushort* qwb  = (ushort*)(ws);                  // 768*256 bf16   (393216 B)
    ushort* pwb  = (ushort*)(ws + 393216);         // 256*256 bf16   (131072 B)
    float*  comb = (float*) (ws + 524288);         // 512*64*64 f32  (8388608 B)
    (void)ws_size; (void)in_sizes; (void)n_in; (void)out_size;

    k_cvt_w<<<dim3(1024), dim3(256), 0, stream>>>(qkv_w, proj_w, qwb, pwb);
    k_comb <<<dim3(512),  dim3(256), 0, stream>>>(mask, rel, bt, comb);
    k_mono <<<dim3(4096), dim3(512), 0, stream>>>(qwb, x, qkv_b, comb, pwb,
                                                  proj_b, out);
}